// Round 1
// baseline (4664.336 us; speedup 1.0000x reference)
//
#include <hip/hip_runtime.h>
#include <math.h>

#define TT 500
#define RTOT 2000   // B*T

__device__ __forceinline__ float4 ld4(const float* p){ return *reinterpret_cast<const float4*>(p); }
__device__ __forceinline__ void st4(float* p, float4 v){ *reinterpret_cast<float4*>(p) = v; }

// ---------------- adj diagonal: softmax(lcb, axis=-1) diag ----------------
__global__ void k_adj(const float* __restrict__ lcb, float* __restrict__ adjd){
  int c = threadIdx.x;
  if (c < 8){
    float m = lcb[c*8];
    for (int j=1;j<8;++j) m = fmaxf(m, lcb[c*8+j]);
    float s = 0.f;
    for (int j=0;j<8;++j) s += expf(lcb[c*8+j]-m);
    adjd[c] = expf(lcb[c*8+c]-m)/s;
  }
}

// ---------------- stage 1: dwconv(d=1)+LN(128)+relu + X@rw1 ----------------
__global__ __launch_bounds__(128) void k_stage1(const float* __restrict__ X,
    const float* __restrict__ w1, const float* __restrict__ cb1,
    const float* __restrict__ s1, const float* __restrict__ b1,
    const float* __restrict__ rw1, const float* __restrict__ rb1,
    float* __restrict__ t1){
  __shared__ float sb[128], qb[128];
  int r = blockIdx.x; int b = r / TT; int t = r % TT;
  int o = threadIdx.x; int ci = o >> 4;
  const float* Xb = X + b*8*TT;
  float v = cb1[o];
  if (t > 0)    v = fmaf(Xb[ci*TT + t-1], w1[o],     v);
  v = fmaf(Xb[ci*TT + t], w1[128+o], v);
  if (t < TT-1) v = fmaf(Xb[ci*TT + t+1], w1[256+o], v);
  sb[o] = v; qb[o] = v*v;
  __syncthreads();
  for (int s=64;s>0;s>>=1){ if (o < s){ sb[o]+=sb[o+s]; qb[o]+=qb[o+s]; } __syncthreads(); }
  float mu = sb[0]*(1.f/128.f);
  float var = qb[0]*(1.f/128.f) - mu*mu;
  float rs = rsqrtf(var + 1e-6f);
  float a = fmaxf((v-mu)*rs*s1[o] + b1[o], 0.f);
  float res = rb1[o];
  for (int c=0;c<8;++c) res = fmaf(Xb[c*TT + t], rw1[c*128+o], res);
  t1[r*128+o] = a + res;
}

// ---------------- stage 2: dwconv(d=2)+LN(2048)+relu + t1@rw2 ----------------
__global__ __launch_bounds__(256) void k_stage2(const float* __restrict__ t1,
    const float* __restrict__ w2, const float* __restrict__ cb2,
    const float* __restrict__ s2, const float* __restrict__ b2,
    const float* __restrict__ rw2, const float* __restrict__ rb2,
    float* __restrict__ t2){
  __shared__ float ld[3][128];
  __shared__ float sb[256], qb[256];
  int r = blockIdx.x; int b = r / TT; int t = r % TT;
  int tid = threadIdx.x;
  for (int j=tid; j<384; j+=256){
    int rr = j >> 7, dd = j & 127;
    int ttv = t + (rr-1)*2;
    ld[rr][dd] = (ttv>=0 && ttv<TT) ? t1[(b*TT+ttv)*128+dd] : 0.f;
  }
  __syncthreads();
  int o0 = tid*8; int c2 = tid>>1;
  float x0 = ld[0][c2], x1 = ld[1][c2], x2 = ld[2][c2];
  float cv[8];
  float ls=0.f, lq=0.f;
  #pragma unroll
  for (int j=0;j<8;++j){
    int o = o0 + j;
    float v = cb2[o];
    v = fmaf(x0, w2[o], v);
    v = fmaf(x1, w2[2048+o], v);
    v = fmaf(x2, w2[4096+o], v);
    cv[j] = v; ls += v; lq += v*v;
  }
  sb[tid]=ls; qb[tid]=lq;
  __syncthreads();
  for (int s=128;s>0;s>>=1){ if(tid<s){sb[tid]+=sb[tid+s];qb[tid]+=qb[tid+s];} __syncthreads(); }
  float mu = sb[0]*(1.f/2048.f);
  float var = qb[0]*(1.f/2048.f)-mu*mu;
  float rs = rsqrtf(var+1e-6f);
  float res[8];
  #pragma unroll
  for (int j=0;j<8;++j) res[j] = rb2[o0+j];
  for (int d=0; d<128; ++d){
    float xa = ld[1][d];
    const float* wr = rw2 + d*2048 + o0;
    #pragma unroll
    for (int j=0;j<8;++j) res[j] = fmaf(xa, wr[j], res[j]);
  }
  #pragma unroll
  for (int j=0;j<8;++j){
    float nr = fmaxf((cv[j]-mu)*rs*s2[o0+j]+b2[o0+j], 0.f);
    t2[(size_t)r*2048+o0+j] = nr + res[j];
  }
}

// ---------------- res3 GEMM: y3 = t2(2000x2048) @ rw3(2048x32768) + rb3 ----------------
__global__ __launch_bounds__(256) void k_gemm_res3(const float* __restrict__ A,
    const float* __restrict__ Bw, const float* __restrict__ bias,
    float* __restrict__ C){
  const int M = RTOT, K = 2048, N = 32768;
  __shared__ __align__(16) float As[8][128];
  __shared__ __align__(16) float Bs[8][128];
  int tid = threadIdx.x;
  int nBase = blockIdx.x*128, mBase = blockIdx.y*128;
  int tx = tid & 15, ty = tid >> 4;
  int arow = tid >> 1, ac = (tid & 1)*4;
  int brow = tid >> 5, bc = (tid & 31)*4;
  bool aval = (mBase + arow) < M;
  const float* Ap = A + (size_t)(mBase+arow)*K + ac;
  const float* Bp = Bw + (size_t)brow*N + nBase + bc;
  float acc[8][8] = {};
  for (int k0=0;k0<K;k0+=8){
    float4 avv = aval ? ld4(Ap + k0) : make_float4(0.f,0.f,0.f,0.f);
    float4 bvv = ld4(Bp + (size_t)k0*N);
    As[ac+0][arow]=avv.x; As[ac+1][arow]=avv.y; As[ac+2][arow]=avv.z; As[ac+3][arow]=avv.w;
    st4(&Bs[brow][bc], bvv);
    __syncthreads();
    #pragma unroll
    for (int kk=0;kk<8;++kk){
      float4 a0 = ld4(&As[kk][ty*8]);
      float4 a1 = ld4(&As[kk][ty*8+4]);
      float4 b0 = ld4(&Bs[kk][tx*4]);
      float4 b1 = ld4(&Bs[kk][64+tx*4]);
      float a[8]={a0.x,a0.y,a0.z,a0.w,a1.x,a1.y,a1.z,a1.w};
      float bb[8]={b0.x,b0.y,b0.z,b0.w,b1.x,b1.y,b1.z,b1.w};
      #pragma unroll
      for (int i=0;i<8;++i)
        #pragma unroll
        for (int j=0;j<8;++j)
          acc[i][j] = fmaf(a[i], bb[j], acc[i][j]);
    }
    __syncthreads();
  }
  float bl0[4], bl1[4];
  #pragma unroll
  for (int j=0;j<4;++j){ bl0[j]=bias[nBase+tx*4+j]; bl1[j]=bias[nBase+64+tx*4+j]; }
  #pragma unroll
  for (int i=0;i<8;++i){
    int m = mBase + ty*8 + i;
    if (m < M){
      float* cp = C + (size_t)m*N + nBase;
      st4(cp + tx*4,      make_float4(acc[i][0]+bl0[0], acc[i][1]+bl0[1], acc[i][2]+bl0[2], acc[i][3]+bl0[3]));
      st4(cp + 64 + tx*4, make_float4(acc[i][4]+bl1[0], acc[i][5]+bl1[1], acc[i][6]+bl1[2], acc[i][7]+bl1[3]));
    }
  }
}

// ---------------- fused stage-3 row: conv3 + LN(32768) + relu + add res3 + diag scale + LN(4096) + relu ----------------
__global__ __launch_bounds__(512) void k_row3(const float* __restrict__ t2,
    const float* __restrict__ w3, const float* __restrict__ cb3,
    const float* __restrict__ s3, const float* __restrict__ b3,
    const float* __restrict__ gs, const float* __restrict__ gb,
    const float* __restrict__ adjd, float* __restrict__ y3){
  extern __shared__ float sm[];
  float* cvb   = sm;            // 32768
  float* wred2 = sm + 32768;    // 128
  int r = blockIdx.x; int t = r % TT;
  int tid = threadIdx.x; int lane = tid & 63; int wid = tid >> 6;
  const float* t2r = t2 + (size_t)r*2048;
  // phase A: conv row into LDS, LN3 partial stats
  float s = 0.f, q = 0.f;
  for (int i=0;i<64;++i){
    int o = tid + (i<<9);
    int ci = o >> 4;
    float v = cb3[o];
    if (t >= 4)    v = fmaf(t2r[ci-8192], w3[o],       v);
    v = fmaf(t2r[ci], w3[32768+o], v);
    if (t < TT-4)  v = fmaf(t2r[ci+8192], w3[65536+o], v);
    cvb[o] = v; s += v; q += v*v;
  }
  for (int off=32; off; off>>=1){ s += __shfl_xor(s, off); q += __shfl_xor(q, off); }
  if (lane==0){ wred2[wid]=s; wred2[64+wid]=q; }
  __syncthreads();
  float S=0.f, Q=0.f;
  for (int w=0; w<8; ++w){ S += wred2[w]; Q += wred2[64+w]; }
  float mu = S*(1.f/32768.f);
  float var = Q*(1.f/32768.f)-mu*mu;
  float rs3 = rsqrtf(var+1e-6f);
  __syncthreads();   // wred2 about to be reused
  // phase B: y = relu(LN3(conv)) + res3; val = adjdiag[c]*y; chunk stats
  float* y3r = y3 + (size_t)r*32768;
  #pragma unroll
  for (int c=0;c<8;++c){
    float ad = adjd[c];
    float ls=0.f, lq=0.f;
    #pragma unroll
    for (int i2=0;i2<8;++i2){
      int o = tid + ((c*8+i2)<<9);
      float v = cvb[o];
      float g = fmaxf((v-mu)*rs3*s3[o]+b3[o], 0.f);
      float val = ad*(g + y3r[o]);
      cvb[o] = val;
      ls += val; lq += val*val;
    }
    for (int off=32; off; off>>=1){ ls += __shfl_xor(ls, off); lq += __shfl_xor(lq, off); }
    if (lane==0){ wred2[c*8+wid]=ls; wred2[64+c*8+wid]=lq; }
  }
  __syncthreads();
  // phase C: per-4096-chunk LN + relu, write flat (in place over res3 buffer)
  #pragma unroll
  for (int c=0;c<8;++c){
    float S2=0.f, Q2=0.f;
    for (int w=0;w<8;++w){ S2+=wred2[c*8+w]; Q2+=wred2[64+c*8+w]; }
    float muc = S2*(1.f/4096.f);
    float varc = Q2*(1.f/4096.f)-muc*muc;
    float rsc = rsqrtf(varc+1e-6f);
    #pragma unroll
    for (int i2=0;i2<8;++i2){
      int o = tid + ((c*8+i2)<<9);
      int f = o & 4095;
      float val = cvb[o];
      y3r[o] = fmaxf((val-muc)*rsc*gs[f]+gb[f], 0.f);
    }
  }
}

// ---------------- seq+geo GEMM (split-K, atomic): sg(2000x256) = flat @ [seq_w | geo_w] ----------------
__global__ __launch_bounds__(256) void k_gemm_sg(const float* __restrict__ A,
    const float* __restrict__ Bseq, const float* __restrict__ Bgeo,
    float* __restrict__ C){
  const int M = RTOT, K = 32768;
  __shared__ __align__(16) float As[16][64];
  __shared__ __align__(16) float Bs[16][64];
  int tid = threadIdx.x;
  int bx = blockIdx.x, by = blockIdx.y, bz = blockIdx.z;
  int mBase = by*64;
  const float* Bsel = (bx < 2) ? Bseq : Bgeo;
  int bn = (bx & 1)*64;
  int tx = tid & 15, ty = tid >> 4;
  int arow = tid >> 2, ac = (tid & 3)*4;
  int brow = tid >> 4, bc = (tid & 15)*4;
  bool aval = (mBase + arow) < M;
  const float* Ap = A + (size_t)(mBase+arow)*K + ac;
  const float* Bp = Bsel + brow*128 + bn + bc;
  float acc[4][4] = {};
  int kStart = bz*4096;
  for (int kk0=0; kk0<4096; kk0+=16){
    int k = kStart + kk0;
    float4 av = aval ? ld4(Ap + k) : make_float4(0.f,0.f,0.f,0.f);
    float4 bv = ld4(Bp + (size_t)k*128);
    As[ac+0][arow]=av.x; As[ac+1][arow]=av.y; As[ac+2][arow]=av.z; As[ac+3][arow]=av.w;
    st4(&Bs[brow][bc], bv);
    __syncthreads();
    #pragma unroll
    for (int kk=0;kk<16;++kk){
      float4 a = ld4(&As[kk][ty*4]);
      float4 b = ld4(&Bs[kk][tx*4]);
      float av_[4]={a.x,a.y,a.z,a.w}, bv_[4]={b.x,b.y,b.z,b.w};
      #pragma unroll
      for (int i=0;i<4;++i)
        #pragma unroll
        for (int j=0;j<4;++j)
          acc[i][j] = fmaf(av_[i], bv_[j], acc[i][j]);
    }
    __syncthreads();
  }
  #pragma unroll
  for (int i=0;i<4;++i){
    int m = mBase + ty*4 + i;
    if (m < M){
      float* cp = C + (size_t)m*256 + bx*64 + tx*4;
      #pragma unroll
      for (int j=0;j<4;++j) atomicAdd(cp+j, acc[i][j]);
    }
  }
}

// ---------------- chunk means: sseq/geo (40x128 each) ----------------
__global__ __launch_bounds__(128) void k_mean(const float* __restrict__ sg,
    const float* __restrict__ sbias, const float* __restrict__ gbias,
    float* __restrict__ sseq, float* __restrict__ geo){
  int blk = blockIdx.x; int b = blk/10, s = blk%10;
  int d = threadIdx.x;
  int base = b*TT + s*50;
  float a1=0.f, a2=0.f;
  for (int i=0;i<50;++i){
    const float* row = sg + (size_t)(base+i)*256;
    a1 += row[d]; a2 += row[128+d];
  }
  sseq[blk*128+d] = a1*(1.f/50.f) + sbias[d];
  geo[blk*128+d]  = a2*(1.f/50.f) + gbias[d];
}

// ---------------- head: decay, LIF scan, attn softmax, FCs ----------------
__global__ __launch_bounds__(256) void k_head(const float* __restrict__ sseq,
    const float* __restrict__ geo, const float* __restrict__ lw,
    const float* __restrict__ lb, const float* __restrict__ aw,
    const float* __restrict__ ab, const float* __restrict__ f1w,
    const float* __restrict__ f1b, const float* __restrict__ f2w,
    const float* __restrict__ f2b, float* __restrict__ out){
  extern __shared__ float sm[];
  float* sseqL = sm;            // 5120
  float* geoL  = sm + 5120;     // 5120
  float* decayL= sm + 10240;    // 5120
  float* spkL  = sm + 15360;    // 5120
  float* featL = sm + 20480;    // 512
  float* alL   = sm + 20992;    // 40
  float* awL   = sm + 21032;    // 40
  float* h1L   = sm + 21072;    // 256
  float* redL  = sm + 21328;    // 8
  int tid = threadIdx.x;
  for (int i=tid;i<5120;i+=256){ sseqL[i]=sseq[i]; geoL[i]=geo[i]; }
  __syncthreads();
  for (int idx=tid; idx<5120; idx+=256){
    int ro = idx>>7, dp = idx&127;
    float sum = lb[dp];
    const float* g = geoL + ro*128;
    for (int dd=0;dd<128;++dd) sum = fmaf(g[dd], lw[dd*128+dp], sum);
    decayL[idx] = 1.f/(1.f+expf(-sum));
  }
  __syncthreads();
  for (int p=tid; p<512; p+=256){
    int b = p>>7, d = p&127;
    float mem = 0.f;
    for (int s=0;s<10;++s){
      int idx = (b*10+s)*128 + d;
      mem = fmaf(mem, decayL[idx], sseqL[idx]);
      float spk = (mem > 0.5f) ? 1.f : 0.f;
      spkL[idx] = spk;
      mem -= 0.5f*spk;
    }
  }
  __syncthreads();
  float lsum = 0.f;
  for (int i=tid;i<5120;i+=256) lsum += spkL[i];
  for (int off=32; off; off>>=1) lsum += __shfl_xor(lsum, off);
  if ((tid&63)==0) redL[tid>>6] = lsum;
  __syncthreads();
  if (tid==0) out[16] = (redL[0]+redL[1]+redL[2]+redL[3])*(1.f/5120.f);
  if (tid < 40){
    float s = ab[0];
    const float* sp = spkL + tid*128;
    for (int dd=0;dd<128;++dd) s = fmaf(sp[dd], aw[dd], s);
    alL[tid] = s;
  }
  __syncthreads();
  if (tid < 4){
    float m = alL[tid*10];
    for (int s=1;s<10;++s) m = fmaxf(m, alL[tid*10+s]);
    float sum=0.f;
    for (int s=0;s<10;++s){ float e = expf(alL[tid*10+s]-m); awL[tid*10+s]=e; sum+=e; }
    float inv = 1.f/sum;
    for (int s=0;s<10;++s) awL[tid*10+s] *= inv;
  }
  __syncthreads();
  for (int p=tid;p<512;p+=256){
    int b=p>>7, d=p&127;
    float f=0.f;
    for (int s=0;s<10;++s) f = fmaf(spkL[(b*10+s)*128+d], awL[b*10+s], f);
    featL[p]=f;
  }
  __syncthreads();
  {
    int b = tid>>6, j = tid&63;
    float v = f1b[j];
    const float* fr = featL + b*128;
    for (int dd=0;dd<128;++dd) v = fmaf(fr[dd], f1w[dd*64+j], v);
    h1L[tid] = fmaxf(v, 0.f);
  }
  __syncthreads();
  if (tid < 16){
    int b = tid>>2, kk = tid&3;
    float v = f2b[kk];
    const float* h = h1L + b*64;
    for (int j=0;j<64;++j) v = fmaf(h[j], f2w[j*4+kk], v);
    out[tid] = v;
  }
}

extern "C" void kernel_launch(void* const* d_in, const int* in_sizes, int n_in,
                              void* d_out, int out_size, void* d_ws, size_t ws_size,
                              hipStream_t stream) {
  const float* X    = (const float*)d_in[0];
  const float* lcb  = (const float*)d_in[2];
  const float* cw1  = (const float*)d_in[3];
  const float* cb1  = (const float*)d_in[4];
  const float* ls1  = (const float*)d_in[5];
  const float* lb1  = (const float*)d_in[6];
  const float* rw1  = (const float*)d_in[7];
  const float* rb1  = (const float*)d_in[8];
  const float* cw2  = (const float*)d_in[9];
  const float* cb2  = (const float*)d_in[10];
  const float* ls2  = (const float*)d_in[11];
  const float* lb2  = (const float*)d_in[12];
  const float* rw2  = (const float*)d_in[13];
  const float* rb2  = (const float*)d_in[14];
  const float* cw3  = (const float*)d_in[15];
  const float* cb3  = (const float*)d_in[16];
  const float* ls3  = (const float*)d_in[17];
  const float* lb3  = (const float*)d_in[18];
  const float* rw3  = (const float*)d_in[19];
  const float* rb3  = (const float*)d_in[20];
  const float* gs   = (const float*)d_in[21];
  const float* gb   = (const float*)d_in[22];
  const float* sw   = (const float*)d_in[23];
  const float* sb   = (const float*)d_in[24];
  const float* gw   = (const float*)d_in[25];
  const float* gbi  = (const float*)d_in[26];
  const float* lw   = (const float*)d_in[27];
  const float* lbv  = (const float*)d_in[28];
  const float* awv  = (const float*)d_in[29];
  const float* abv  = (const float*)d_in[30];
  const float* f1w  = (const float*)d_in[31];
  const float* f1b  = (const float*)d_in[32];
  const float* f2w  = (const float*)d_in[33];
  const float* f2b  = (const float*)d_in[34];
  float* out = (float*)d_out;

  float* ws   = (float*)d_ws;
  float* adjd = ws;
  float* t1   = ws + 64;                       // 2000*128
  float* t2   = t1 + (size_t)RTOT*128;         // 2000*2048
  float* y3   = t2 + (size_t)RTOT*2048;        // 2000*32768 (res3 -> flat, in place)
  float* sg   = y3 + (size_t)RTOT*32768;       // 2000*256
  float* sseq = sg + (size_t)RTOT*256;         // 40*128
  float* geo  = sseq + 40*128;                 // 40*128

  (void)hipFuncSetAttribute(reinterpret_cast<const void*>(k_row3),
      hipFuncAttributeMaxDynamicSharedMemorySize, 131584);
  (void)hipFuncSetAttribute(reinterpret_cast<const void*>(k_head),
      hipFuncAttributeMaxDynamicSharedMemorySize, 85344);

  k_adj<<<1, 64, 0, stream>>>(lcb, adjd);
  k_stage1<<<RTOT, 128, 0, stream>>>(X, cw1, cb1, ls1, lb1, rw1, rb1, t1);
  k_stage2<<<RTOT, 256, 0, stream>>>(t1, cw2, cb2, ls2, lb2, rw2, rb2, t2);
  k_gemm_res3<<<dim3(256,16), 256, 0, stream>>>(t2, rw3, rb3, y3);
  k_row3<<<RTOT, 512, 131584, stream>>>(t2, cw3, cb3, ls3, lb3, gs, gb, adjd, y3);
  hipMemsetAsync(sg, 0, (size_t)RTOT*256*sizeof(float), stream);
  k_gemm_sg<<<dim3(4,32,8), 256, 0, stream>>>(y3, sw, gw, sg);
  k_mean<<<40, 128, 0, stream>>>(sg, sb, gbi, sseq, geo);
  k_head<<<1, 256, 85344, stream>>>(sseq, geo, lw, lbv, awv, abv, f1w, f1b, f2w, f2b, out);
}

// Round 4
// 2552.608 us; speedup vs baseline: 1.8273x; 1.8273x over previous
//
#include <hip/hip_runtime.h>
#include <math.h>

#define TT 500
#define RTOT 2000   // B*T

using bf16x8 = __attribute__((ext_vector_type(8))) short;     // 8 bf16 = 4 VGPR
using f32x4  = __attribute__((ext_vector_type(4))) float;
using us8    = __attribute__((ext_vector_type(8))) unsigned short;

__device__ __forceinline__ float4 ld4(const float* p){ return *reinterpret_cast<const float4*>(p); }
__device__ __forceinline__ void st4(float* p, float4 v){ *reinterpret_cast<float4*>(p) = v; }

// bf16 RNE helpers (manual, avoids header type friction)
__device__ __forceinline__ unsigned short f2b(float x){
  unsigned int u = __builtin_bit_cast(unsigned int, x);
  unsigned int r = u + 0x7FFFu + ((u >> 16) & 1u);
  return (unsigned short)(r >> 16);
}
__device__ __forceinline__ float b2f(unsigned short h){
  return __builtin_bit_cast(float, (unsigned int)h << 16);
}

__device__ __forceinline__ void gll16(const void* g, void* l){
  __builtin_amdgcn_global_load_lds(
      (const __attribute__((address_space(1))) void*)g,
      (__attribute__((address_space(3))) void*)l, 16, 0, 0);
}
__device__ __forceinline__ bf16x8 ldfrag(const void* base, int byteoff){
  return *(const bf16x8*)((const char*)base + byteoff);
}
__device__ __forceinline__ f32x4 mma(bf16x8 a, bf16x8 b, f32x4 c){
  return __builtin_amdgcn_mfma_f32_16x16x32_bf16(a, b, c, 0, 0, 0);
}

// ---------------- adj diagonal ----------------
__global__ void k_adj(const float* __restrict__ lcb, float* __restrict__ adjd){
  int c = threadIdx.x;
  if (c < 8){
    float m = lcb[c*8];
    for (int j=1;j<8;++j) m = fmaxf(m, lcb[c*8+j]);
    float s = 0.f;
    for (int j=0;j<8;++j) s += expf(lcb[c*8+j]-m);
    adjd[c] = expf(lcb[c*8+c]-m)/s;
  }
}

// ---------------- stage 1 ----------------
__global__ __launch_bounds__(128) void k_stage1(const float* __restrict__ X,
    const float* __restrict__ w1, const float* __restrict__ cb1,
    const float* __restrict__ s1, const float* __restrict__ b1,
    const float* __restrict__ rw1, const float* __restrict__ rb1,
    float* __restrict__ t1){
  __shared__ float sb[128], qb[128];
  int r = blockIdx.x; int b = r / TT; int t = r % TT;
  int o = threadIdx.x; int ci = o >> 4;
  const float* Xb = X + b*8*TT;
  float v = cb1[o];
  if (t > 0)    v = fmaf(Xb[ci*TT + t-1], w1[o],     v);
  v = fmaf(Xb[ci*TT + t], w1[128+o], v);
  if (t < TT-1) v = fmaf(Xb[ci*TT + t+1], w1[256+o], v);
  sb[o] = v; qb[o] = v*v;
  __syncthreads();
  for (int s=64;s>0;s>>=1){ if (o < s){ sb[o]+=sb[o+s]; qb[o]+=qb[o+s]; } __syncthreads(); }
  float mu = sb[0]*(1.f/128.f);
  float var = qb[0]*(1.f/128.f) - mu*mu;
  float rs = rsqrtf(var + 1e-6f);
  float a = fmaxf((v-mu)*rs*s1[o] + b1[o], 0.f);
  float res = rb1[o];
  for (int c=0;c<8;++c) res = fmaf(Xb[c*TT + t], rw1[c*128+o], res);
  t1[r*128+o] = a + res;
}

// ---------------- stage 2: + split bf16 outputs ----------------
__global__ __launch_bounds__(256) void k_stage2m(const float* __restrict__ t1,
    const float* __restrict__ w2, const float* __restrict__ cb2,
    const float* __restrict__ s2, const float* __restrict__ b2,
    const float* __restrict__ rw2, const float* __restrict__ rb2,
    float* __restrict__ t2f, unsigned short* __restrict__ t2h,
    unsigned short* __restrict__ t2l){
  __shared__ float ld[3][128];
  __shared__ float sb[256], qb[256];
  int r = blockIdx.x; int b = r / TT; int t = r % TT;
  int tid = threadIdx.x;
  for (int j=tid; j<384; j+=256){
    int rr = j >> 7, dd = j & 127;
    int ttv = t + (rr-1)*2;
    ld[rr][dd] = (ttv>=0 && ttv<TT) ? t1[(b*TT+ttv)*128+dd] : 0.f;
  }
  __syncthreads();
  int o0 = tid*8; int c2 = tid>>1;
  float x0 = ld[0][c2], x1 = ld[1][c2], x2 = ld[2][c2];
  float cv[8];
  float ls=0.f, lq=0.f;
  #pragma unroll
  for (int j=0;j<8;++j){
    int o = o0 + j;
    float v = cb2[o];
    v = fmaf(x0, w2[o], v);
    v = fmaf(x1, w2[2048+o], v);
    v = fmaf(x2, w2[4096+o], v);
    cv[j] = v; ls += v; lq += v*v;
  }
  sb[tid]=ls; qb[tid]=lq;
  __syncthreads();
  for (int s=128;s>0;s>>=1){ if(tid<s){sb[tid]+=sb[tid+s];qb[tid]+=qb[tid+s];} __syncthreads(); }
  float mu = sb[0]*(1.f/2048.f);
  float var = qb[0]*(1.f/2048.f)-mu*mu;
  float rs = rsqrtf(var+1e-6f);
  float res[8];
  #pragma unroll
  for (int j=0;j<8;++j) res[j] = rb2[o0+j];
  for (int d=0; d<128; ++d){
    float xa = ld[1][d];
    const float* wr = rw2 + d*2048 + o0;
    #pragma unroll
    for (int j=0;j<8;++j) res[j] = fmaf(xa, wr[j], res[j]);
  }
  #pragma unroll
  for (int j=0;j<8;++j){
    float nr = fmaxf((cv[j]-mu)*rs*s2[o0+j]+b2[o0+j], 0.f);
    float val = nr + res[j];
    size_t oo = (size_t)r*2048+o0+j;
    t2f[oo] = val;
    unsigned short h = f2b(val);
    t2h[oo] = h;
    t2l[oo] = f2b(val - b2f(h));
  }
}

// ---------------- transpose + hi/lo split: in[R][C] f32 -> out[(C)+off][R] bf16 ----------------
__global__ __launch_bounds__(256) void k_tsplit(const float* __restrict__ in,
    unsigned short* __restrict__ outh, unsigned short* __restrict__ outl,
    int R, int Cc, int rowOff){
  __shared__ float ld[256][33];
  int t = threadIdx.x;
  int kT = blockIdx.x * 256, nT = blockIdx.y * 32;
  #pragma unroll
  for (int p=0;p<8;++p){
    int row = p*32 + (t>>3);
    int c4 = (t&7)*4;
    float4 v = ld4(in + (size_t)(kT+row)*Cc + nT + c4);
    ld[row][c4]=v.x; ld[row][c4+1]=v.y; ld[row][c4+2]=v.z; ld[row][c4+3]=v.w;
  }
  __syncthreads();
  int nloc = t >> 3, kc = t & 7;
  size_t obase = (size_t)(nT + nloc + rowOff)*R + kT + kc*32;
  #pragma unroll
  for (int b=0;b<4;++b){
    us8 hv, lv;
    #pragma unroll
    for (int e=0;e<8;++e){
      float x = ld[kc*32 + b*8 + e][nloc];
      unsigned short h = f2b(x);
      hv[e] = h;
      lv[e] = f2b(x - b2f(h));
    }
    *(us8*)(outh + obase + b*8) = hv;
    *(us8*)(outl + obase + b*8) = lv;
  }
}

// ---------------- res3 MFMA GEMM: C(2000x32768) = t2(2048x2048) @ Bt(32768x2048)^T, 3-term split ----------------
__global__ __launch_bounds__(256) void k_gemm3m(
    const unsigned short* __restrict__ Ah, const unsigned short* __restrict__ Al,
    const unsigned short* __restrict__ Bh, const unsigned short* __restrict__ Bl,
    const float* __restrict__ bias,
    unsigned short* __restrict__ Ch, unsigned short* __restrict__ Cl){
  __shared__ unsigned short sA_h[4096], sA_l[4096], sB_h[4096], sB_l[4096];
  const int K = 2048;
  int tid = threadIdx.x, l = tid & 63, w = tid >> 6;
  // XCD-chunked bijective swizzle (4096 wgs % 8 == 0)
  int id = blockIdx.y * 16 + blockIdx.x;
  int work = (id & 7) * 512 + (id >> 3);
  int mBase = (work & 15) * 128, nBase = (work >> 4) * 128;
  // staging: chunk idx = (s*4+w)*64 + l; row=idx>>2, c=idx&3, src chunk XOR-swizzled
  int i0 = w*64 + l, i1 = (4+w)*64 + l;
  int r0 = i0 >> 2, c0 = (i0 & 3) ^ (r0 & 3);
  int r1 = i1 >> 2, c1 = (i1 & 3) ^ (r1 & 3);
  size_t aof0 = (size_t)(mBase + r0)*K + c0*8;
  size_t aof1 = (size_t)(mBase + r1)*K + c1*8;
  size_t bof0 = (size_t)(nBase + r0)*K + c0*8;
  size_t bof1 = (size_t)(nBase + r1)*K + c1*8;
  int ls0 = w*1024, ls1 = (4+w)*1024;
  int g = l >> 4, lr = l & 15;
  int wrow = (w >> 1)*64, wcol = (w & 1)*64;
  int ao[4], bo[4];
  #pragma unroll
  for (int i=0;i<4;++i){
    int ra = wrow + i*16 + lr; ao[i] = ra*64 + ((g ^ (ra & 3))*16);
    int rb = wcol + i*16 + lr; bo[i] = rb*64 + ((g ^ (rb & 3))*16);
  }
  f32x4 acc[4][4] = {};
  for (int k0 = 0; k0 < K; k0 += 32){
    gll16(Ah + aof0 + k0, (char*)sA_h + ls0);
    gll16(Ah + aof1 + k0, (char*)sA_h + ls1);
    gll16(Al + aof0 + k0, (char*)sA_l + ls0);
    gll16(Al + aof1 + k0, (char*)sA_l + ls1);
    gll16(Bh + bof0 + k0, (char*)sB_h + ls0);
    gll16(Bh + bof1 + k0, (char*)sB_h + ls1);
    gll16(Bl + bof0 + k0, (char*)sB_l + ls0);
    gll16(Bl + bof1 + k0, (char*)sB_l + ls1);
    __syncthreads();
    bf16x8 fAh[4], fAl[4], fBh[4], fBl[4];
    #pragma unroll
    for (int i=0;i<4;++i){
      fAh[i] = ldfrag(sA_h, ao[i]); fAl[i] = ldfrag(sA_l, ao[i]);
      fBh[i] = ldfrag(sB_h, bo[i]); fBl[i] = ldfrag(sB_l, bo[i]);
    }
    #pragma unroll
    for (int i=0;i<4;++i)
      #pragma unroll
      for (int j=0;j<4;++j){
        acc[i][j] = mma(fAh[i], fBh[j], acc[i][j]);
        acc[i][j] = mma(fAh[i], fBl[j], acc[i][j]);
        acc[i][j] = mma(fAl[i], fBh[j], acc[i][j]);
      }
    __syncthreads();
  }
  #pragma unroll
  for (int i=0;i<4;++i){
    int rbase = mBase + wrow + i*16 + g*4;
    #pragma unroll
    for (int j=0;j<4;++j){
      int col = nBase + wcol + j*16 + lr;
      float bv = bias[col];
      #pragma unroll
      for (int q=0;q<4;++q){
        int row = rbase + q;
        if (row < RTOT){
          float v = acc[i][j][q] + bv;
          unsigned short h = f2b(v);
          Ch[(size_t)row*32768 + col] = h;
          Cl[(size_t)row*32768 + col] = f2b(v - b2f(h));
        }
      }
    }
  }
}

// ---------------- seq|geo MFMA GEMM (split-K=16, atomic f32): sg = flat @ [sw|gw] ----------------
__global__ __launch_bounds__(256) void k_sgm(
    const unsigned short* __restrict__ Ah, const unsigned short* __restrict__ Al,
    const unsigned short* __restrict__ Bh, const unsigned short* __restrict__ Bl,
    float* __restrict__ C){
  __shared__ unsigned short sA_h[4096], sA_l[4096], sB_h[4096], sB_l[4096];
  const size_t K = 32768;
  int tid = threadIdx.x, l = tid & 63, w = tid >> 6;
  int id = (blockIdx.z*2 + blockIdx.y)*16 + blockIdx.x;
  int work = (id & 7)*64 + (id >> 3);
  int mBase = (work & 15)*128;
  int rest = work >> 4;
  int nBase = (rest & 1)*128;
  int kc = rest >> 1;
  int i0 = w*64 + l, i1 = (4+w)*64 + l;
  int r0 = i0 >> 2, c0 = (i0 & 3) ^ (r0 & 3);
  int r1 = i1 >> 2, c1 = (i1 & 3) ^ (r1 & 3);
  size_t kS = (size_t)kc*2048;
  size_t aof0 = (size_t)(mBase + r0)*K + kS + c0*8;
  size_t aof1 = (size_t)(mBase + r1)*K + kS + c1*8;
  size_t bof0 = (size_t)(nBase + r0)*K + kS + c0*8;
  size_t bof1 = (size_t)(nBase + r1)*K + kS + c1*8;
  int ls0 = w*1024, ls1 = (4+w)*1024;
  int g = l >> 4, lr = l & 15;
  int wrow = (w >> 1)*64, wcol = (w & 1)*64;
  int ao[4], bo[4];
  #pragma unroll
  for (int i=0;i<4;++i){
    int ra = wrow + i*16 + lr; ao[i] = ra*64 + ((g ^ (ra & 3))*16);
    int rb = wcol + i*16 + lr; bo[i] = rb*64 + ((g ^ (rb & 3))*16);
  }
  f32x4 acc[4][4] = {};
  for (int k0 = 0; k0 < 2048; k0 += 32){
    gll16(Ah + aof0 + k0, (char*)sA_h + ls0);
    gll16(Ah + aof1 + k0, (char*)sA_h + ls1);
    gll16(Al + aof0 + k0, (char*)sA_l + ls0);
    gll16(Al + aof1 + k0, (char*)sA_l + ls1);
    gll16(Bh + bof0 + k0, (char*)sB_h + ls0);
    gll16(Bh + bof1 + k0, (char*)sB_h + ls1);
    gll16(Bl + bof0 + k0, (char*)sB_l + ls0);
    gll16(Bl + bof1 + k0, (char*)sB_l + ls1);
    __syncthreads();
    bf16x8 fAh[4], fAl[4], fBh[4], fBl[4];
    #pragma unroll
    for (int i=0;i<4;++i){
      fAh[i] = ldfrag(sA_h, ao[i]); fAl[i] = ldfrag(sA_l, ao[i]);
      fBh[i] = ldfrag(sB_h, bo[i]); fBl[i] = ldfrag(sB_l, bo[i]);
    }
    #pragma unroll
    for (int i=0;i<4;++i)
      #pragma unroll
      for (int j=0;j<4;++j){
        acc[i][j] = mma(fAh[i], fBh[j], acc[i][j]);
        acc[i][j] = mma(fAh[i], fBl[j], acc[i][j]);
        acc[i][j] = mma(fAl[i], fBh[j], acc[i][j]);
      }
    __syncthreads();
  }
  #pragma unroll
  for (int i=0;i<4;++i){
    int rbase = mBase + wrow + i*16 + g*4;
    #pragma unroll
    for (int j=0;j<4;++j){
      int col = nBase + wcol + j*16 + lr;
      #pragma unroll
      for (int q=0;q<4;++q){
        int row = rbase + q;
        if (row < RTOT) atomicAdd(&C[(size_t)row*256 + col], acc[i][j][q]);
      }
    }
  }
}

// ---------------- fused stage-3 row (split-bf16 res in, split-bf16 flat out) ----------------
__global__ __launch_bounds__(512) void k_row3b(const float* __restrict__ t2,
    const float* __restrict__ w3, const float* __restrict__ cb3,
    const float* __restrict__ s3, const float* __restrict__ b3,
    const float* __restrict__ gs, const float* __restrict__ gb,
    const float* __restrict__ adjd,
    unsigned short* __restrict__ y3h, unsigned short* __restrict__ y3l){
  extern __shared__ float sm[];
  float* cvb   = sm;            // 32768
  float* wred2 = sm + 32768;    // 128
  int r = blockIdx.x; int t = r % TT;
  int tid = threadIdx.x; int lane = tid & 63; int wid = tid >> 6;
  const float* t2r = t2 + (size_t)r*2048;
  float s = 0.f, q = 0.f;
  for (int i=0;i<64;++i){
    int o = tid + (i<<9);
    int ci = o >> 4;
    float v = cb3[o];
    if (t >= 4)    v = fmaf(t2r[ci-8192], w3[o],       v);
    v = fmaf(t2r[ci], w3[32768+o], v);
    if (t < TT-4)  v = fmaf(t2r[ci+8192], w3[65536+o], v);
    cvb[o] = v; s += v; q += v*v;
  }
  for (int off=32; off; off>>=1){ s += __shfl_xor(s, off); q += __shfl_xor(q, off); }
  if (lane==0){ wred2[wid]=s; wred2[64+wid]=q; }
  __syncthreads();
  float S=0.f, Q=0.f;
  for (int ww=0; ww<8; ++ww){ S += wred2[ww]; Q += wred2[64+ww]; }
  float mu = S*(1.f/32768.f);
  float var = Q*(1.f/32768.f)-mu*mu;
  float rs3 = rsqrtf(var+1e-6f);
  __syncthreads();
  const unsigned short* rh = y3h + (size_t)r*32768;
  const unsigned short* rl = y3l + (size_t)r*32768;
  #pragma unroll
  for (int c=0;c<8;++c){
    float ad = adjd[c];
    float ls=0.f, lq=0.f;
    #pragma unroll
    for (int i2=0;i2<8;++i2){
      int o = tid + ((c*8+i2)<<9);
      float v = cvb[o];
      float g_ = fmaxf((v-mu)*rs3*s3[o]+b3[o], 0.f);
      float resv = b2f(rh[o]) + b2f(rl[o]);
      float val = ad*(g_ + resv);
      cvb[o] = val;
      ls += val; lq += val*val;
    }
    for (int off=32; off; off>>=1){ ls += __shfl_xor(ls, off); lq += __shfl_xor(lq, off); }
    if (lane==0){ wred2[c*8+wid]=ls; wred2[64+c*8+wid]=lq; }
  }
  __syncthreads();
  unsigned short* wh = y3h + (size_t)r*32768;
  unsigned short* wl = y3l + (size_t)r*32768;
  #pragma unroll
  for (int c=0;c<8;++c){
    float S2=0.f, Q2=0.f;
    for (int ww=0;ww<8;++ww){ S2+=wred2[c*8+ww]; Q2+=wred2[64+c*8+ww]; }
    float muc = S2*(1.f/4096.f);
    float varc = Q2*(1.f/4096.f)-muc*muc;
    float rsc = rsqrtf(varc+1e-6f);
    #pragma unroll
    for (int i2=0;i2<8;++i2){
      int o = tid + ((c*8+i2)<<9);
      int f = o & 4095;
      float val = cvb[o];
      float ov = fmaxf((val-muc)*rsc*gs[f]+gb[f], 0.f);
      unsigned short h = f2b(ov);
      wh[o] = h;
      wl[o] = f2b(ov - b2f(h));
    }
  }
}

// ---------------- chunk means ----------------
__global__ __launch_bounds__(128) void k_mean(const float* __restrict__ sg,
    const float* __restrict__ sbias, const float* __restrict__ gbias,
    float* __restrict__ sseq, float* __restrict__ geo){
  int blk = blockIdx.x; int b = blk/10, s = blk%10;
  int d = threadIdx.x;
  int base = b*TT + s*50;
  float a1=0.f, a2=0.f;
  for (int i=0;i<50;++i){
    const float* row = sg + (size_t)(base+i)*256;
    a1 += row[d]; a2 += row[128+d];
  }
  sseq[blk*128+d] = a1*(1.f/50.f) + sbias[d];
  geo[blk*128+d]  = a2*(1.f/50.f) + gbias[d];
}

// ---------------- head ----------------
__global__ __launch_bounds__(256) void k_head(const float* __restrict__ sseq,
    const float* __restrict__ geo, const float* __restrict__ lw,
    const float* __restrict__ lb, const float* __restrict__ aw,
    const float* __restrict__ ab, const float* __restrict__ f1w,
    const float* __restrict__ f1b, const float* __restrict__ f2w,
    const float* __restrict__ f2b_, float* __restrict__ out){
  extern __shared__ float sm[];
  float* sseqL = sm;
  float* geoL  = sm + 5120;
  float* decayL= sm + 10240;
  float* spkL  = sm + 15360;
  float* featL = sm + 20480;
  float* alL   = sm + 20992;
  float* awL   = sm + 21032;
  float* h1L   = sm + 21072;
  float* redL  = sm + 21328;
  int tid = threadIdx.x;
  for (int i=tid;i<5120;i+=256){ sseqL[i]=sseq[i]; geoL[i]=geo[i]; }
  __syncthreads();
  for (int idx=tid; idx<5120; idx+=256){
    int ro = idx>>7, dp = idx&127;
    float sum = lb[dp];
    const float* g = geoL + ro*128;
    for (int dd=0;dd<128;++dd) sum = fmaf(g[dd], lw[dd*128+dp], sum);
    decayL[idx] = 1.f/(1.f+expf(-sum));
  }
  __syncthreads();
  for (int p=tid; p<512; p+=256){
    int b = p>>7, d = p&127;
    float mem = 0.f;
    for (int s=0;s<10;++s){
      int idx = (b*10+s)*128 + d;
      mem = fmaf(mem, decayL[idx], sseqL[idx]);
      float spk = (mem > 0.5f) ? 1.f : 0.f;
      spkL[idx] = spk;
      mem -= 0.5f*spk;
    }
  }
  __syncthreads();
  float lsum = 0.f;
  for (int i=tid;i<5120;i+=256) lsum += spkL[i];
  for (int off=32; off; off>>=1) lsum += __shfl_xor(lsum, off);
  if ((tid&63)==0) redL[tid>>6] = lsum;
  __syncthreads();
  if (tid==0) out[16] = (redL[0]+redL[1]+redL[2]+redL[3])*(1.f/5120.f);
  if (tid < 40){
    float s = ab[0];
    const float* sp = spkL + tid*128;
    for (int dd=0;dd<128;++dd) s = fmaf(sp[dd], aw[dd], s);
    alL[tid] = s;
  }
  __syncthreads();
  if (tid < 4){
    float m = alL[tid*10];
    for (int s=1;s<10;++s) m = fmaxf(m, alL[tid*10+s]);
    float sum=0.f;
    for (int s=0;s<10;++s){ float e = expf(alL[tid*10+s]-m); awL[tid*10+s]=e; sum+=e; }
    float inv = 1.f/sum;
    for (int s=0;s<10;++s) awL[tid*10+s] *= inv;
  }
  __syncthreads();
  for (int p=tid;p<512;p+=256){
    int b=p>>7, d=p&127;
    float f=0.f;
    for (int s=0;s<10;++s) f = fmaf(spkL[(b*10+s)*128+d], awL[b*10+s], f);
    featL[p]=f;
  }
  __syncthreads();
  {
    int b = tid>>6, j = tid&63;
    float v = f1b[j];
    const float* fr = featL + b*128;
    for (int dd=0;dd<128;++dd) v = fmaf(fr[dd], f1w[dd*64+j], v);
    h1L[tid] = fmaxf(v, 0.f);
  }
  __syncthreads();
  if (tid < 16){
    int b = tid>>2, kk = tid&3;
    float v = f2b_[kk];
    const float* h = h1L + b*64;
    for (int j=0;j<64;++j) v = fmaf(h[j], f2w[j*4+kk], v);
    out[tid] = v;
  }
}

extern "C" void kernel_launch(void* const* d_in, const int* in_sizes, int n_in,
                              void* d_out, int out_size, void* d_ws, size_t ws_size,
                              hipStream_t stream) {
  const float* X    = (const float*)d_in[0];
  const float* lcb  = (const float*)d_in[2];
  const float* cw1  = (const float*)d_in[3];
  const float* cb1  = (const float*)d_in[4];
  const float* ls1  = (const float*)d_in[5];
  const float* lb1  = (const float*)d_in[6];
  const float* rw1  = (const float*)d_in[7];
  const float* rb1  = (const float*)d_in[8];
  const float* cw2  = (const float*)d_in[9];
  const float* cb2  = (const float*)d_in[10];
  const float* ls2  = (const float*)d_in[11];
  const float* lb2  = (const float*)d_in[12];
  const float* rw2  = (const float*)d_in[13];
  const float* rb2  = (const float*)d_in[14];
  const float* cw3  = (const float*)d_in[15];
  const float* cb3  = (const float*)d_in[16];
  const float* ls3  = (const float*)d_in[17];
  const float* lb3  = (const float*)d_in[18];
  const float* rw3  = (const float*)d_in[19];
  const float* rb3  = (const float*)d_in[20];
  const float* gs   = (const float*)d_in[21];
  const float* gb   = (const float*)d_in[22];
  const float* sw   = (const float*)d_in[23];
  const float* sb   = (const float*)d_in[24];
  const float* gw   = (const float*)d_in[25];
  const float* gbi  = (const float*)d_in[26];
  const float* lw   = (const float*)d_in[27];
  const float* lbv  = (const float*)d_in[28];
  const float* awv  = (const float*)d_in[29];
  const float* abv  = (const float*)d_in[30];
  const float* f1w  = (const float*)d_in[31];
  const float* f1b  = (const float*)d_in[32];
  const float* f2w  = (const float*)d_in[33];
  const float* f2b_ = (const float*)d_in[34];
  float* out = (float*)d_out;

  char* W = (char*)d_ws;
  size_t off = 0;
  auto alloc = [&](size_t bytes) -> char* {
    char* p = W + off;
    off += (bytes + 255) & ~(size_t)255;
    return p;
  };
  float* adjd = (float*)alloc(64*4);
  float* t1   = (float*)alloc((size_t)RTOT*128*4);
  float* t2f  = (float*)alloc((size_t)RTOT*2048*4);
  unsigned short* t2h = (unsigned short*)alloc((size_t)2048*2048*2);
  unsigned short* t2l = (unsigned short*)alloc((size_t)2048*2048*2);
  unsigned short* y3h = (unsigned short*)alloc((size_t)2048*32768*2);
  unsigned short* y3l = (unsigned short*)alloc((size_t)2048*32768*2);
  unsigned short* Bt3h = (unsigned short*)alloc((size_t)32768*2048*2);
  unsigned short* Bt3l = (unsigned short*)alloc((size_t)32768*2048*2);
  unsigned short* BtSh = (unsigned short*)alloc((size_t)256*32768*2);
  unsigned short* BtSl = (unsigned short*)alloc((size_t)256*32768*2);
  float* sg   = (float*)alloc((size_t)RTOT*256*4);
  float* sseq = (float*)alloc(40*128*4);
  float* geo  = (float*)alloc(40*128*4);

  (void)hipFuncSetAttribute(reinterpret_cast<const void*>(k_row3b),
      hipFuncAttributeMaxDynamicSharedMemorySize, 131584);
  (void)hipFuncSetAttribute(reinterpret_cast<const void*>(k_head),
      hipFuncAttributeMaxDynamicSharedMemorySize, 85344);

  // zero the padded tail rows (ws is re-poisoned 0xAA before every call)
  hipMemsetAsync(t2h + (size_t)RTOT*2048, 0, (size_t)48*2048*2, stream);
  hipMemsetAsync(t2l + (size_t)RTOT*2048, 0, (size_t)48*2048*2, stream);
  hipMemsetAsync(y3h + (size_t)RTOT*32768, 0, (size_t)48*32768*2, stream);
  hipMemsetAsync(y3l + (size_t)RTOT*32768, 0, (size_t)48*32768*2, stream);
  hipMemsetAsync(sg, 0, (size_t)RTOT*256*4, stream);

  k_adj<<<1, 64, 0, stream>>>(lcb, adjd);
  k_stage1<<<RTOT, 128, 0, stream>>>(X, cw1, cb1, ls1, lb1, rw1, rb1, t1);
  k_stage2m<<<RTOT, 256, 0, stream>>>(t1, cw2, cb2, ls2, lb2, rw2, rb2, t2f, t2h, t2l);
  k_tsplit<<<dim3(8,1024), 256, 0, stream>>>(rw3, Bt3h, Bt3l, 2048, 32768, 0);
  k_tsplit<<<dim3(128,4), 256, 0, stream>>>(sw, BtSh, BtSl, 32768, 128, 0);
  k_tsplit<<<dim3(128,4), 256, 0, stream>>>(gw, BtSh, BtSl, 32768, 128, 128);
  k_gemm3m<<<dim3(16,256), 256, 0, stream>>>(t2h, t2l, Bt3h, Bt3l, rb3, y3h, y3l);
  k_row3b<<<RTOT, 512, 131584, stream>>>(t2f, cw3, cb3, ls3, lb3, gs, gb, adjd, y3h, y3l);
  k_sgm<<<dim3(16,2,16), 256, 0, stream>>>(y3h, y3l, BtSh, BtSl, sg);
  k_mean<<<40, 128, 0, stream>>>(sg, sb, gbi, sseq, geo);
  k_head<<<1, 256, 85344, stream>>>(sseq, geo, lw, lbv, awv, abv, f1w, f1b, f2w, f2b_, out);
}